// Round 10
// baseline (41.753 us; speedup 1.0000x reference)
//
#include <hip/hip_runtime.h>

#define HW 224
#define CHW (HW*HW)

__global__ __launch_bounds__(256) void patch_conv_kernel(
    const float* __restrict__ X,    // [B][3][224][224]
    const float* __restrict__ Wt,   // [3][3][3][3] OIHW
    const float* __restrict__ Bv,   // [3]
    const float* __restrict__ P,    // [3136][48]
    float* __restrict__ out)        // [B][196][768]
{
    const int tid  = threadIdx.x;
    const int lane = tid & 63;
    const int wv   = tid >> 6;
    const int b    = blockIdx.y;
    const int y0   = blockIdx.x * 16 + wv * 4;  // multiple of 4; wave owns rows y0..y0+3
    const int x0   = lane * 4;                  // 0..252
    const bool act = (x0 < HW);                 // lanes 56..63 assist shfl only

    // ---- weights: wave-uniform -> SGPRs
    float w[81];
    #pragma unroll
    for (int i = 0; i < 81; ++i) w[i] = Wt[i];

    const float* Xb = X + (size_t)b * (3 * CHW);

    // ---- issue ALL 18 X loads up-front (rows y0-1..y0+4 x 3 channels)
    float4 v[3][6];
    #pragma unroll
    for (int ci = 0; ci < 3; ++ci) {
        #pragma unroll
        for (int rj = 0; rj < 6; ++rj) {
            const int ry = y0 - 1 + rj;
            float4 t = make_float4(0.f, 0.f, 0.f, 0.f);
            if ((unsigned)ry < HW && act)
                t = *(const float4*)(Xb + ci * CHW + ry * HW + x0);
            v[ci][rj] = t;
        }
    }

    // ---- 12 P loads up-front (all 4 rows in the SAME fine row: y0 % 4 == 0)
    const int nf = (y0 >> 2) * 56 + lane;       // lane == x0>>2
    float4 pr[4][3];
    #pragma unroll
    for (int rr = 0; rr < 4; ++rr) {
        #pragma unroll
        for (int co = 0; co < 3; ++co) {
            float4 t = make_float4(0.f, 0.f, 0.f, 0.f);
            if (act)
                t = *(const float4*)(P + nf * 48 + co * 16 + rr * 4);
            pr[rr][co] = t;
        }
    }

    // ---- edges via shfl (all 64 lanes participate)
    float win[3][6][6];
    #pragma unroll
    for (int ci = 0; ci < 3; ++ci) {
        #pragma unroll
        for (int rj = 0; rj < 6; ++rj) {
            float lf = __shfl_up(v[ci][rj].w, 1);
            float rt = __shfl_down(v[ci][rj].x, 1);
            if (lane == 0) lf = 0.f;
            if (x0 + 4 >= HW) rt = 0.f;
            win[ci][rj][0] = lf;
            win[ci][rj][1] = v[ci][rj].x; win[ci][rj][2] = v[ci][rj].y;
            win[ci][rj][3] = v[ci][rj].z; win[ci][rj][4] = v[ci][rj].w;
            win[ci][rj][5] = rt;
        }
    }

    if (!act) return;

    // ---- accumulators: bias + P
    float acc[4][3][4];
    #pragma unroll
    for (int rr = 0; rr < 4; ++rr) {
        #pragma unroll
        for (int co = 0; co < 3; ++co) {
            const float bb = Bv[co];
            acc[rr][co][0] = bb + pr[rr][co].x;
            acc[rr][co][1] = bb + pr[rr][co].y;
            acc[rr][co][2] = bb + pr[rr][co].z;
            acc[rr][co][3] = bb + pr[rr][co].w;
        }
    }

    // ---- 1296 FMAs: row rr uses win[ci][rr+ky]
    #pragma unroll
    for (int ci = 0; ci < 3; ++ci) {
        #pragma unroll
        for (int ky = 0; ky < 3; ++ky) {
            #pragma unroll
            for (int co = 0; co < 3; ++co) {
                const float w0 = w[((co * 3 + ci) * 3 + ky) * 3 + 0];
                const float w1 = w[((co * 3 + ci) * 3 + ky) * 3 + 1];
                const float w2 = w[((co * 3 + ci) * 3 + ky) * 3 + 2];
                #pragma unroll
                for (int rr = 0; rr < 4; ++rr) {
                    const float* r = win[ci][rr + ky];
                    #pragma unroll
                    for (int j = 0; j < 4; ++j)
                        acc[rr][co][j] += w0 * r[j] + w1 * r[j + 1] + w2 * r[j + 2];
                }
            }
        }
    }

    // ---- stores: all 4 rows share the same coarse patch (y0 % 4 == 0)
    const int nc = (y0 >> 4) * 14 + (x0 >> 4);
    float* opb = out + (size_t)b * (196 * 768) + nc * 768 + (x0 & 15);
    #pragma unroll
    for (int rr = 0; rr < 4; ++rr) {
        float* op = opb + ((y0 + rr) & 15) * 16;
        #pragma unroll
        for (int co = 0; co < 3; ++co)
            *(float4*)(op + co * 256) =
                make_float4(acc[rr][co][0], acc[rr][co][1],
                            acc[rr][co][2], acc[rr][co][3]);
    }
}

extern "C" void kernel_launch(void* const* d_in, const int* in_sizes, int n_in,
                              void* d_out, int out_size, void* d_ws, size_t ws_size,
                              hipStream_t stream) {
    const float* X  = (const float*)d_in[0];
    const float* Wt = (const float*)d_in[1];
    const float* Bv = (const float*)d_in[2];
    const float* P  = (const float*)d_in[3];
    float* out = (float*)d_out;

    // wave = 4 rows (one fine row); block = 4 waves = 16 rows; 14 x-blocks x 128 images
    dim3 grid(14, 128);
    patch_conv_kernel<<<grid, 256, 0, stream>>>(X, Wt, Bv, P, out);
}

// Round 11
// 39.837 us; speedup vs baseline: 1.0481x; 1.0481x over previous
//
#include <hip/hip_runtime.h>

#define HW 224
#define CHW (HW*HW)

__global__ __launch_bounds__(256) void patch_conv_kernel(
    const float* __restrict__ X,    // [B][3][224][224]
    const float* __restrict__ Wt,   // [3][3][3][3] OIHW
    const float* __restrict__ Bv,   // [3]
    const float* __restrict__ P,    // [3136][48]
    float* __restrict__ out)        // [B][196][768]
{
    const int tid  = threadIdx.x;
    const int lane = tid & 63;
    const int wv   = tid >> 6;
    const int b    = blockIdx.y;
    const int Y0   = blockIdx.x * 8;            // block owns rows Y0..Y0+7 = 2 fine rows
    const int y0   = Y0 + wv * 2;               // even; wave owns rows y0, y0+1
    const int x0   = lane * 4;                  // 0..252
    const bool act = (x0 < HW);                 // lanes 56..63 assist shfl/staging only

    // ---- P staged per block: 2 fine rows x 56 nf x 48, stride 49 (21.4 KB)
    // read pattern lane-stride 49 -> bank 17*lane mod 32 -> conflict-free
    __shared__ float pl[2 * 56 * 49];

    // 1) stage-load P into regs FIRST (oldest in vmcnt queue -> LDS writes
    //    drain these while the X loads below stay in flight)
    float4 s[6];
    const float4* Ps = (const float4*)(P + blockIdx.x * (2 * 56 * 48));
    #pragma unroll
    for (int k = 0; k < 6; ++k) {               // 1344 float4 total
        const int i = tid + k * 256;
        s[k] = (i < 1344) ? Ps[i] : make_float4(0.f, 0.f, 0.f, 0.f);
    }

    // 2) weights (wave-uniform -> SGPRs) and ALL 12 X loads up-front
    float w[81];
    #pragma unroll
    for (int i = 0; i < 81; ++i) w[i] = Wt[i];
    const float bias[3] = { Bv[0], Bv[1], Bv[2] };

    const float* Xb = X + (size_t)b * (3 * CHW);
    float4 v[3][4];
    #pragma unroll
    for (int ci = 0; ci < 3; ++ci) {
        #pragma unroll
        for (int rj = 0; rj < 4; ++rj) {
            const int ry = y0 - 1 + rj;
            float4 t = make_float4(0.f, 0.f, 0.f, 0.f);
            if ((unsigned)ry < HW && act)
                t = *(const float4*)(Xb + ci * CHW + ry * HW + x0);
            v[ci][rj] = t;
        }
    }

    // 3) write P to LDS (waits only on stage loads), then barrier
    #pragma unroll
    for (int k = 0; k < 6; ++k) {
        const int i = tid + k * 256;
        if (i < 1344) {
            const int r = i / 12;
            const int c = (i - r * 12) * 4;
            float* d = &pl[r * 49 + c];
            d[0] = s[k].x; d[1] = s[k].y; d[2] = s[k].z; d[3] = s[k].w;
        }
    }
    __syncthreads();

    // 4) edges via shfl (all 64 lanes participate)
    float win[3][4][6];
    #pragma unroll
    for (int ci = 0; ci < 3; ++ci) {
        #pragma unroll
        for (int rj = 0; rj < 4; ++rj) {
            float lf = __shfl_up(v[ci][rj].w, 1);
            float rt = __shfl_down(v[ci][rj].x, 1);
            if (lane == 0) lf = 0.f;
            if (x0 + 4 >= HW) rt = 0.f;
            win[ci][rj][0] = lf;
            win[ci][rj][1] = v[ci][rj].x; win[ci][rj][2] = v[ci][rj].y;
            win[ci][rj][3] = v[ci][rj].z; win[ci][rj][4] = v[ci][rj].w;
            win[ci][rj][5] = rt;
        }
    }

    if (!act) return;                           // no barriers past this point

    // 5) accumulators: bias + P from LDS (12 conflict-free ds_read_b32)
    const int frl  = wv >> 1;                   // fine row within block
    const int sub0 = (wv & 1) * 8;              // (y0&3)*4
    const float* pb = &pl[(frl * 56 + lane) * 49 + sub0];
    float acc[2][3][4];
    #pragma unroll
    for (int rr = 0; rr < 2; ++rr)
        #pragma unroll
        for (int co = 0; co < 3; ++co)
            #pragma unroll
            for (int j = 0; j < 4; ++j)
                acc[rr][co][j] = bias[co] + pb[co * 16 + rr * 4 + j];

    // 6) 648 FMAs: row0 uses win[.][ky], row1 uses win[.][ky+1]
    #pragma unroll
    for (int ci = 0; ci < 3; ++ci) {
        #pragma unroll
        for (int ky = 0; ky < 3; ++ky) {
            const float* r0 = win[ci][ky];
            const float* r1 = win[ci][ky + 1];
            #pragma unroll
            for (int co = 0; co < 3; ++co) {
                const float w0 = w[((co * 3 + ci) * 3 + ky) * 3 + 0];
                const float w1 = w[((co * 3 + ci) * 3 + ky) * 3 + 1];
                const float w2 = w[((co * 3 + ci) * 3 + ky) * 3 + 2];
                #pragma unroll
                for (int j = 0; j < 4; ++j) {
                    acc[0][co][j] += w0 * r0[j] + w1 * r0[j + 1] + w2 * r0[j + 2];
                    acc[1][co][j] += w0 * r1[j] + w1 * r1[j + 1] + w2 * r1[j + 2];
                }
            }
        }
    }

    // 7) stores: both rows share the same coarse patch (y0 even)
    const int nc = (y0 >> 4) * 14 + (x0 >> 4);
    float* opb = out + (size_t)b * (196 * 768) + nc * 768 + (x0 & 15);
    #pragma unroll
    for (int rr = 0; rr < 2; ++rr) {
        float* op = opb + ((y0 + rr) & 15) * 16;
        #pragma unroll
        for (int co = 0; co < 3; ++co)
            *(float4*)(op + co * 256) =
                make_float4(acc[rr][co][0], acc[rr][co][1],
                            acc[rr][co][2], acc[rr][co][3]);
    }
}

extern "C" void kernel_launch(void* const* d_in, const int* in_sizes, int n_in,
                              void* d_out, int out_size, void* d_ws, size_t ws_size,
                              hipStream_t stream) {
    const float* X  = (const float*)d_in[0];
    const float* Wt = (const float*)d_in[1];
    const float* Bv = (const float*)d_in[2];
    const float* P  = (const float*)d_in[3];
    float* out = (float*)d_out;

    // wave = 2 rows; block = 4 waves = 8 rows = 2 fine rows; 28 x-blocks x 128 images
    dim3 grid(28, 128);
    patch_conv_kernel<<<grid, 256, 0, stream>>>(X, Wt, Bv, P, out);
}